// Round 2
// baseline (20903.709 us; speedup 1.0000x reference)
//
#include <hip/hip_runtime.h>
#include <math.h>

// Fixed instance constants.
#define Nn 4096          // n = m * tmax
#define BSc 32           // batch size (border rows)
#define Mm (Nn + BSc)    // bordered rows: 4128
#define NB 128           // block size
#define NBLK 33          // block-rows: 32 full + 1 border (32 rows)
#define NK 32            // factorization steps (block columns of N)
#define TILE_ELEMS (NB * NB)

// Packed lower-block-triangular storage: tile(i,j) for 0<=j<=i<=32,
// stored column-major by block-column. 561 tiles * 64KB = 36.8 MB.
__device__ __forceinline__ size_t tile_off(int i, int j) {
  return ((size_t)(j * NBLK - (j * (j - 1)) / 2 + (i - j))) * TILE_ELEMS;
}

__device__ __forceinline__ int blk_rows(int i) { return (i == NBLK - 1) ? BSc : NB; }

// ---------------------------------------------------------------------------
// prep: fill every stored tile from the virtual bordered matrix:
//   rows<N, cols<N : K + diag(Sigma)
//   border rows    : mu - Y   (cols < N),  0 (corner)
//   rows beyond Mm within a tile: 0
// ---------------------------------------------------------------------------
__global__ __launch_bounds__(256) void prep(const float* __restrict__ Y,
                                            const float* __restrict__ mu,
                                            const float* __restrict__ Kp,
                                            const float* __restrict__ Sg,
                                            float* __restrict__ W) {
  int bid = blockIdx.x;
  int j = 0;
  while (j + 1 < NBLK) {
    int nxt = (j + 1) * NBLK - ((j + 1) * j) / 2;
    if (bid < nxt) break;
    ++j;
  }
  int start = j * NBLK - (j * (j - 1)) / 2;
  int i = j + (bid - start);
  float* T = W + tile_off(i, j);
  int tid = threadIdx.x;
  for (int idx = tid; idx < TILE_ELEMS; idx += 256) {
    int li = idx >> 7, lj = idx & 127;
    int gr = i * NB + li, gc = j * NB + lj;
    float v = 0.0f;
    if (gr < Nn) {                       // main block (gc < Nn guaranteed: j<=i<32)
      v = Kp[(size_t)gr * Nn + gc];
      if (gr == gc) v += Sg[(size_t)gr * Nn + gr];
    } else {
      int b = gr - Nn;
      if (b < BSc && gc < Nn) v = mu[gc] - Y[(size_t)b * Nn + gc];
      // corner & out-of-range rows: 0
    }
    T[idx] = v;
  }
}

// ---------------------------------------------------------------------------
// potf2: factor tile(k,k) in LDS. Unscaled-column elimination (LDL-style),
// one barrier per column; scale on store. Diag stores sqrt(d).
// ---------------------------------------------------------------------------
__global__ __launch_bounds__(256) void potf2(float* __restrict__ W, int k) {
  __shared__ float T[NB][NB + 1];
  __shared__ float dsh[NB], dinvsh[NB];
  float* G = W + tile_off(k, k);
  int tid = threadIdx.x;
  for (int idx = tid; idx < TILE_ELEMS; idx += 256) {
    T[idx >> 7][idx & 127] = G[idx];
  }
  __syncthreads();
  int lane = tid & 63, wid = tid >> 6;
  for (int j = 0; j < NB - 1; ++j) {
    float inv = 1.0f / T[j][j];
    for (int jj = j + 1 + lane; jj < NB; jj += 64) {
      float w = T[jj][j] * inv;
      for (int ii = j + 1 + wid; ii < NB; ii += 4) {
        T[ii][jj] -= T[ii][j] * w;
      }
    }
    __syncthreads();
  }
  if (tid < NB) {
    float dj = sqrtf(T[tid][tid]);
    dsh[tid] = dj;
    dinvsh[tid] = 1.0f / dj;
  }
  __syncthreads();
  for (int idx = tid; idx < TILE_ELEMS; idx += 256) {
    int i = idx >> 7, j = idx & 127;
    float v;
    if (i > j)       v = T[i][j] * dinvsh[j];
    else if (i == j) v = dsh[i];
    else continue;
    G[idx] = v;
  }
}

// ---------------------------------------------------------------------------
// trsm: tile(i,k) = tile(i,k) * L_kk^{-T}, i = k+1+blockIdx.x.
// Columns eliminated with one barrier per column.
// ---------------------------------------------------------------------------
__global__ __launch_bounds__(256) void trsm(float* __restrict__ W, int k) {
  __shared__ float T[NB][NB + 1];
  __shared__ float X[NB][NB + 1];
  __shared__ float dinvsh[NB];
  int tid = threadIdx.x;
  int i = k + 1 + blockIdx.x;
  int rows = blk_rows(i);
  const float* Gd = W + tile_off(k, k);
  float* Gx = W + tile_off(i, k);
  for (int idx = tid; idx < TILE_ELEMS; idx += 256) {
    int r = idx >> 7, c = idx & 127;
    T[r][c] = Gd[idx];
    X[r][c] = (r < rows) ? Gx[idx] : 0.0f;
  }
  __syncthreads();
  if (tid < NB) dinvsh[tid] = 1.0f / T[tid][tid];
  __syncthreads();
  int lane = tid & 63, wid = tid >> 6;
  for (int j = 0; j < NB - 1; ++j) {
    float dinv = dinvsh[j];
    for (int p = j + 1 + lane; p < NB; p += 64) {
      float w = T[p][j] * dinv;
      for (int r = wid; r < NB; r += 4) {
        X[r][p] -= X[r][j] * w;
      }
    }
    __syncthreads();
  }
  for (int idx = tid; idx < TILE_ELEMS; idx += 256) {
    int r = idx >> 7, c = idx & 127;
    if (r < rows) Gx[idx] = X[r][c] * dinvsh[c];
  }
}

// ---------------------------------------------------------------------------
// syrk/gemm: tile(i,j) -= P_i * P_j^T with P = block-column k panels.
// i = k+1+blockIdx.x, j = k+1+blockIdx.y, lower tiles only (i >= j).
// 128x128 tile, 8x8 per thread, K = 128.
// ---------------------------------------------------------------------------
__global__ __launch_bounds__(256) void syrk(float* __restrict__ W, int k) {
  int i = k + 1 + blockIdx.x, j = k + 1 + blockIdx.y;
  if (i < j) return;
  int rows_i = blk_rows(i), rows_j = blk_rows(j);
  const float* Pa = W + tile_off(i, k);
  const float* Pb = W + tile_off(j, k);
  float* C = W + tile_off(i, j);
  __shared__ float As[NB][NB + 1];
  __shared__ float Bs[NB][NB + 1];
  int tid = threadIdx.x;
  for (int idx = tid; idx < TILE_ELEMS; idx += 256) {
    int r = idx >> 7, p = idx & 127;
    As[p][r] = (r < rows_i) ? Pa[idx] : 0.0f;
    Bs[p][r] = (r < rows_j) ? Pb[idx] : 0.0f;
  }
  __syncthreads();
  int tx = tid & 15, ty = tid >> 4;
  float acc[8][8];
#pragma unroll
  for (int m = 0; m < 8; ++m)
#pragma unroll
    for (int n = 0; n < 8; ++n) acc[m][n] = 0.0f;
  for (int p = 0; p < NB; ++p) {
    float a[8], b[8];
#pragma unroll
    for (int m = 0; m < 8; ++m) a[m] = As[p][ty + 16 * m];
#pragma unroll
    for (int n = 0; n < 8; ++n) b[n] = Bs[p][tx + 16 * n];
#pragma unroll
    for (int m = 0; m < 8; ++m)
#pragma unroll
      for (int n = 0; n < 8; ++n) acc[m][n] += a[m] * b[n];
  }
#pragma unroll
  for (int m = 0; m < 8; ++m) {
    int r = ty + 16 * m;
    if (r >= rows_i) continue;
#pragma unroll
    for (int n = 0; n < 8; ++n) {
      int c = tx + 16 * n;
      if (c < rows_j) C[r * NB + c] -= acc[m][n];
    }
  }
}

// ---------------------------------------------------------------------------
// finalize: quad = -trace(corner tile(32,32)); 0.5*logdet = sum log diag(L);
// out = quad/(2*bs) + 0.5*logdet + 0.5*tmax*log(2*pi)
// ---------------------------------------------------------------------------
__global__ __launch_bounds__(256) void finalize(const float* __restrict__ W,
                                                const int* __restrict__ bsp,
                                                const int* __restrict__ tmaxp,
                                                float* __restrict__ out) {
  __shared__ float rl[4], rq[4];
  int tid = threadIdx.x;
  float lsum = 0.0f;
  for (int d = tid; d < Nn; d += 256) {
    int db = d >> 7, dl = d & 127;
    lsum += logf(W[tile_off(db, db) + (size_t)dl * NB + dl]);
  }
  float qsum = 0.0f;
  if (tid < BSc) qsum = W[tile_off(NBLK - 1, NBLK - 1) + (size_t)tid * NB + tid];
  for (int o = 32; o > 0; o >>= 1) {
    lsum += __shfl_down(lsum, o, 64);
    qsum += __shfl_down(qsum, o, 64);
  }
  int lane = tid & 63, wid = tid >> 6;
  if (lane == 0) { rl[wid] = lsum; rq[wid] = qsum; }
  __syncthreads();
  if (tid == 0) {
    float Lt = rl[0] + rl[1] + rl[2] + rl[3];
    float Qt = rq[0] + rq[1] + rq[2] + rq[3];
    float bsf = (float)bsp[0];
    float tmaxf = (float)tmaxp[0];
    out[0] = -Qt / (2.0f * bsf) + Lt + 0.5f * tmaxf * logf(6.283185307179586f);
  }
}

extern "C" void kernel_launch(void* const* d_in, const int* in_sizes, int n_in,
                              void* d_out, int out_size, void* d_ws, size_t ws_size,
                              hipStream_t stream) {
  const float* Y   = (const float*)d_in[0];
  const float* mu  = (const float*)d_in[1];
  const float* Kp  = (const float*)d_in[2];
  const float* Sg  = (const float*)d_in[3];
  const int*   bsp = (const int*)d_in[4];
  const int*   tmp_= (const int*)d_in[5];
  float* W   = (float*)d_ws;   // packed tiles: 561 * 64KB = 36.8 MB
  float* out = (float*)d_out;

  const int n_tiles = NBLK * NBLK - (NBLK - 1) * NBLK / 2;  // 561
  prep<<<n_tiles, 256, 0, stream>>>(Y, mu, Kp, Sg, W);

  for (int k = 0; k < NK; ++k) {
    potf2<<<1, 256, 0, stream>>>(W, k);
    int T = NBLK - (k + 1);                  // 32-k tiles below the diagonal
    trsm<<<T, 256, 0, stream>>>(W, k);
    dim3 g(T, T);
    syrk<<<g, 256, 0, stream>>>(W, k);
  }
  finalize<<<1, 256, 0, stream>>>(W, bsp, tmp_, out);
}

// Round 3
// 5952.491 us; speedup vs baseline: 3.5118x; 3.5118x over previous
//
#include <hip/hip_runtime.h>
#include <math.h>

// Fixed instance constants.
#define Nn 4096          // n = m * tmax
#define BSc 32           // batch size (border rows)
#define NB 128           // block size
#define NBB 32           // sub-block for recursive factorization
#define NBLK 33          // block-rows: 32 full + 1 border (32 rows)
#define NK 32            // factorization steps
#define TILE_ELEMS (NB * NB)

// Packed lower-block-triangular storage: tile(i,j), 0<=j<=i<=32, stored
// column-major by block-column. 561 tiles * 64KB = 36.8 MB.
__device__ __forceinline__ size_t tile_off(int i, int j) {
  return ((size_t)(j * NBLK - (j * (j - 1)) / 2 + (i - j))) * TILE_ELEMS;
}
__device__ __forceinline__ int blk_rows(int i) { return (i == NBLK - 1) ? BSc : NB; }

// ---------------------------------------------------------------------------
// prep: fill stored tiles from the virtual bordered matrix.
// ---------------------------------------------------------------------------
__global__ __launch_bounds__(256) void prep(const float* __restrict__ Y,
                                            const float* __restrict__ mu,
                                            const float* __restrict__ Kp,
                                            const float* __restrict__ Sg,
                                            float* __restrict__ W) {
  int bid = blockIdx.x;
  int j = 0;
  while (j + 1 < NBLK) {
    int nxt = (j + 1) * NBLK - ((j + 1) * j) / 2;
    if (bid < nxt) break;
    ++j;
  }
  int start = j * NBLK - (j * (j - 1)) / 2;
  int i = j + (bid - start);
  float* T = W + tile_off(i, j);
  int tid = threadIdx.x;
  for (int idx = tid; idx < TILE_ELEMS; idx += 256) {
    int li = idx >> 7, lj = idx & 127;
    int gr = i * NB + li, gc = j * NB + lj;
    float v = 0.0f;
    if (gr < Nn) {
      v = Kp[(size_t)gr * Nn + gc];
      if (gr == gc) v += Sg[(size_t)gr * Nn + gr];
    } else {
      int b = gr - Nn;
      if (b < BSc && gc < Nn) v = mu[gc] - Y[(size_t)b * Nn + gc];
    }
    T[idx] = v;
  }
}

// ---------------------------------------------------------------------------
// potf2: factor tile(k,k) with recursive 32-blocking.
//  A) 32x32 diag: one wave, register Cholesky-Crout with __shfl broadcasts.
//  B) 32-col panel solve: one row per thread, register recurrence.
//  C) trailing syrk: 4x4 register tiles, lower tiles only.
// ---------------------------------------------------------------------------
__global__ __launch_bounds__(256) void potf2(float* __restrict__ W, int k) {
  __shared__ float T[NB][NB + 1];
  __shared__ float dinv_sh[NBB];
  float* G = W + tile_off(k, k);
  int tid = threadIdx.x;
  for (int idx = tid; idx < TILE_ELEMS / 4; idx += 256) {
    float4 v = ((const float4*)G)[idx];
    int r = idx >> 5, c = (idx & 31) * 4;
    T[r][c] = v.x; T[r][c + 1] = v.y; T[r][c + 2] = v.z; T[r][c + 3] = v.w;
  }
  __syncthreads();
  int lane = tid & 63, wid = tid >> 6;
  for (int kb = 0; kb < 4; ++kb) {
    int o = kb * NBB;
    // --- A: factor 32x32 diagonal sub-block (wave 0, registers + shuffles) ---
    if (wid == 0) {
      int i = lane & 31;
      float cc[NBB];
#pragma unroll
      for (int p = 0; p < NBB; ++p) cc[p] = T[o + i][o + p];
#pragma unroll
      for (int j = 0; j < NBB; ++j) {
        float s = cc[j];
#pragma unroll
        for (int p = 0; p < NBB; ++p) {
          if (p < j) s -= cc[p] * __shfl(cc[p], j, 64);
        }
        float sj = __shfl(s, j, 64);
        float d = sqrtf(sj);
        if (i == j) cc[j] = d;
        else if (i > j) cc[j] = s / d;
      }
      if (lane < 32) {
#pragma unroll
        for (int p = 0; p < NBB; ++p) {
          if (p <= i) T[o + i][o + p] = cc[p];
        }
      }
    }
    __syncthreads();
    if (tid < NBB) dinv_sh[tid] = 1.0f / T[o + tid][o + tid];
    __syncthreads();
    int R = NB - o - NBB;   // trailing rows: 96, 64, 32, 0
    if (R > 0) {
      // --- B: solve trailing rows of this tile against the 32x32 triangle ---
      if (tid < R) {
        int r = o + NBB + tid;
        float x[NBB];
#pragma unroll
        for (int p = 0; p < NBB; ++p) x[p] = T[r][o + p];
#pragma unroll
        for (int j = 0; j < NBB; ++j) {
          float s = x[j];
#pragma unroll
          for (int p = 0; p < NBB; ++p) {
            if (p < j) s -= x[p] * T[o + j][o + p];
          }
          x[j] = s * dinv_sh[j];
        }
#pragma unroll
        for (int p = 0; p < NBB; ++p) T[r][o + p] = x[p];
      }
      __syncthreads();
      // --- C: trailing rank-32 update, lower 4x4 tiles only ---
      int TL = R >> 2;
      int ntile = TL * (TL + 1) / 2;
      for (int t = tid; t < ntile; t += 256) {
        int ti = (int)((sqrtf(8.0f * t + 1.0f) - 1.0f) * 0.5f);
        while ((ti + 1) * (ti + 2) / 2 <= t) ++ti;
        while (ti * (ti + 1) / 2 > t) --ti;
        int tj = t - ti * (ti + 1) / 2;
        int tr = o + NBB + ti * 4, tc = o + NBB + tj * 4;
        float acc[4][4];
#pragma unroll
        for (int m = 0; m < 4; ++m)
#pragma unroll
          for (int n = 0; n < 4; ++n) acc[m][n] = 0.0f;
        for (int p = 0; p < NBB; ++p) {
          float a0 = T[tr][o + p], a1 = T[tr + 1][o + p],
                a2 = T[tr + 2][o + p], a3 = T[tr + 3][o + p];
          float b0 = T[tc][o + p], b1 = T[tc + 1][o + p],
                b2 = T[tc + 2][o + p], b3 = T[tc + 3][o + p];
          acc[0][0] += a0 * b0; acc[0][1] += a0 * b1; acc[0][2] += a0 * b2; acc[0][3] += a0 * b3;
          acc[1][0] += a1 * b0; acc[1][1] += a1 * b1; acc[1][2] += a1 * b2; acc[1][3] += a1 * b3;
          acc[2][0] += a2 * b0; acc[2][1] += a2 * b1; acc[2][2] += a2 * b2; acc[2][3] += a2 * b3;
          acc[3][0] += a3 * b0; acc[3][1] += a3 * b1; acc[3][2] += a3 * b2; acc[3][3] += a3 * b3;
        }
#pragma unroll
        for (int m = 0; m < 4; ++m)
#pragma unroll
          for (int n = 0; n < 4; ++n) T[tr + m][tc + n] -= acc[m][n];
      }
    }
    __syncthreads();
  }
  // store lower triangle (incl diag)
  for (int idx = tid; idx < TILE_ELEMS; idx += 256) {
    int r = idx >> 7, c = idx & 127;
    if (c <= r) G[idx] = T[r][c];
  }
}

// ---------------------------------------------------------------------------
// trsm: tile(i,k) <- tile(i,k) * L_kk^{-T}, blocked forward substitution.
// Per 32-col block: register-tiled GEMM update + row-parallel register solve.
// ---------------------------------------------------------------------------
__global__ __launch_bounds__(256) void trsm(float* __restrict__ W, int k) {
  __shared__ float Td[NB][NB + 1];
  __shared__ float X[NB][NB + 1];
  __shared__ float dinv_sh[NB];
  int tid = threadIdx.x;
  int i = k + 1 + blockIdx.x;
  const float* Gd = W + tile_off(k, k);
  float* Gx = W + tile_off(i, k);
  for (int idx = tid; idx < TILE_ELEMS / 4; idx += 256) {
    float4 v = ((const float4*)Gd)[idx];
    float4 u = ((const float4*)Gx)[idx];
    int r = idx >> 5, c = (idx & 31) * 4;
    Td[r][c] = v.x; Td[r][c + 1] = v.y; Td[r][c + 2] = v.z; Td[r][c + 3] = v.w;
    X[r][c] = u.x;  X[r][c + 1] = u.y;  X[r][c + 2] = u.z;  X[r][c + 3] = u.w;
  }
  __syncthreads();
  if (tid < NB) dinv_sh[tid] = 1.0f / Td[tid][tid];
  __syncthreads();
  int rtile = (tid >> 3) * 4;   // 0..124
  int ctile = (tid & 7) * 4;    // 0..28
  for (int jb = 0; jb < 4; ++jb) {
    int o = jb * NBB;
    if (jb > 0) {
      // X[:, o..o+31] -= X[:, 0..o-1] * Td[o..o+31][0..o-1]^T
      float acc[4][4];
#pragma unroll
      for (int m = 0; m < 4; ++m)
#pragma unroll
        for (int n = 0; n < 4; ++n) acc[m][n] = 0.0f;
      for (int p = 0; p < o; ++p) {
        float a0 = X[rtile][p], a1 = X[rtile + 1][p],
              a2 = X[rtile + 2][p], a3 = X[rtile + 3][p];
        float b0 = Td[o + ctile][p], b1 = Td[o + ctile + 1][p],
              b2 = Td[o + ctile + 2][p], b3 = Td[o + ctile + 3][p];
        acc[0][0] += a0 * b0; acc[0][1] += a0 * b1; acc[0][2] += a0 * b2; acc[0][3] += a0 * b3;
        acc[1][0] += a1 * b0; acc[1][1] += a1 * b1; acc[1][2] += a1 * b2; acc[1][3] += a1 * b3;
        acc[2][0] += a2 * b0; acc[2][1] += a2 * b1; acc[2][2] += a2 * b2; acc[2][3] += a2 * b3;
        acc[3][0] += a3 * b0; acc[3][1] += a3 * b1; acc[3][2] += a3 * b2; acc[3][3] += a3 * b3;
      }
#pragma unroll
      for (int m = 0; m < 4; ++m)
#pragma unroll
        for (int n = 0; n < 4; ++n) X[rtile + m][o + ctile + n] -= acc[m][n];
      __syncthreads();
    }
    // row-parallel solve against 32x32 triangle at (o,o)
    if (tid < NB) {
      int r = tid;
      float x[NBB];
#pragma unroll
      for (int p = 0; p < NBB; ++p) x[p] = X[r][o + p];
#pragma unroll
      for (int j = 0; j < NBB; ++j) {
        float s = x[j];
#pragma unroll
        for (int p = 0; p < NBB; ++p) {
          if (p < j) s -= x[p] * Td[o + j][o + p];
        }
        x[j] = s * dinv_sh[o + j];
      }
#pragma unroll
      for (int p = 0; p < NBB; ++p) X[r][o + p] = x[p];
    }
    __syncthreads();
  }
  for (int idx = tid; idx < TILE_ELEMS / 4; idx += 256) {
    int r = idx >> 5, c = (idx & 31) * 4;
    float4 u;
    u.x = X[r][c]; u.y = X[r][c + 1]; u.z = X[r][c + 2]; u.w = X[r][c + 3];
    ((float4*)Gx)[idx] = u;
  }
}

// ---------------------------------------------------------------------------
// syrk: tile(i,j) -= P_i * P_j^T (unchanged from working version).
// ---------------------------------------------------------------------------
__global__ __launch_bounds__(256) void syrk(float* __restrict__ W, int k) {
  int i = k + 1 + blockIdx.x, j = k + 1 + blockIdx.y;
  if (i < j) return;
  int rows_i = blk_rows(i), rows_j = blk_rows(j);
  const float* Pa = W + tile_off(i, k);
  const float* Pb = W + tile_off(j, k);
  float* C = W + tile_off(i, j);
  __shared__ float As[NB][NB + 1];
  __shared__ float Bs[NB][NB + 1];
  int tid = threadIdx.x;
  for (int idx = tid; idx < TILE_ELEMS; idx += 256) {
    int r = idx >> 7, p = idx & 127;
    As[p][r] = (r < rows_i) ? Pa[idx] : 0.0f;
    Bs[p][r] = (r < rows_j) ? Pb[idx] : 0.0f;
  }
  __syncthreads();
  int tx = tid & 15, ty = tid >> 4;
  float acc[8][8];
#pragma unroll
  for (int m = 0; m < 8; ++m)
#pragma unroll
    for (int n = 0; n < 8; ++n) acc[m][n] = 0.0f;
  for (int p = 0; p < NB; ++p) {
    float a[8], b[8];
#pragma unroll
    for (int m = 0; m < 8; ++m) a[m] = As[p][ty + 16 * m];
#pragma unroll
    for (int n = 0; n < 8; ++n) b[n] = Bs[p][tx + 16 * n];
#pragma unroll
    for (int m = 0; m < 8; ++m)
#pragma unroll
      for (int n = 0; n < 8; ++n) acc[m][n] += a[m] * b[n];
  }
#pragma unroll
  for (int m = 0; m < 8; ++m) {
    int r = ty + 16 * m;
    if (r >= rows_i) continue;
#pragma unroll
    for (int n = 0; n < 8; ++n) {
      int c = tx + 16 * n;
      if (c < rows_j) C[r * NB + c] -= acc[m][n];
    }
  }
}

// ---------------------------------------------------------------------------
// finalize: -lml from corner trace and diag of L.
// ---------------------------------------------------------------------------
__global__ __launch_bounds__(256) void finalize(const float* __restrict__ W,
                                                const int* __restrict__ bsp,
                                                const int* __restrict__ tmaxp,
                                                float* __restrict__ out) {
  __shared__ float rl[4], rq[4];
  int tid = threadIdx.x;
  float lsum = 0.0f;
  for (int d = tid; d < Nn; d += 256) {
    int db = d >> 7, dl = d & 127;
    lsum += logf(W[tile_off(db, db) + (size_t)dl * NB + dl]);
  }
  float qsum = 0.0f;
  if (tid < BSc) qsum = W[tile_off(NBLK - 1, NBLK - 1) + (size_t)tid * NB + tid];
  for (int o = 32; o > 0; o >>= 1) {
    lsum += __shfl_down(lsum, o, 64);
    qsum += __shfl_down(qsum, o, 64);
  }
  int lane = tid & 63, wid = tid >> 6;
  if (lane == 0) { rl[wid] = lsum; rq[wid] = qsum; }
  __syncthreads();
  if (tid == 0) {
    float Lt = rl[0] + rl[1] + rl[2] + rl[3];
    float Qt = rq[0] + rq[1] + rq[2] + rq[3];
    float bsf = (float)bsp[0];
    float tmaxf = (float)tmaxp[0];
    out[0] = -Qt / (2.0f * bsf) + Lt + 0.5f * tmaxf * logf(6.283185307179586f);
  }
}

extern "C" void kernel_launch(void* const* d_in, const int* in_sizes, int n_in,
                              void* d_out, int out_size, void* d_ws, size_t ws_size,
                              hipStream_t stream) {
  const float* Y   = (const float*)d_in[0];
  const float* mu  = (const float*)d_in[1];
  const float* Kp  = (const float*)d_in[2];
  const float* Sg  = (const float*)d_in[3];
  const int*   bsp = (const int*)d_in[4];
  const int*   tmp_= (const int*)d_in[5];
  float* W   = (float*)d_ws;
  float* out = (float*)d_out;

  const int n_tiles = NBLK * NBLK - (NBLK - 1) * NBLK / 2;  // 561
  prep<<<n_tiles, 256, 0, stream>>>(Y, mu, Kp, Sg, W);

  for (int k = 0; k < NK; ++k) {
    potf2<<<1, 256, 0, stream>>>(W, k);
    int T = NBLK - (k + 1);
    trsm<<<T, 256, 0, stream>>>(W, k);
    dim3 g(T, T);
    syrk<<<g, 256, 0, stream>>>(W, k);
  }
  finalize<<<1, 256, 0, stream>>>(W, bsp, tmp_, out);
}

// Round 4
// 4059.651 us; speedup vs baseline: 5.1491x; 1.4663x over previous
//
#include <hip/hip_runtime.h>
#include <math.h>

// Fixed instance constants.
#define Nn 4096          // n = m * tmax
#define BSc 32           // batch size (border rows)
#define NB 128           // block size
#define NBB 32           // sub-block for recursive factorization
#define NBLK 33          // block-rows: 32 full + 1 border (32 rows)
#define NK 32            // factorization steps
#define TILE_ELEMS (NB * NB)
#define NTILES 561       // NBLK*(NBLK+1)/2 lower tiles

typedef float f32x4 __attribute__((ext_vector_type(4)));
typedef short bf16x8 __attribute__((ext_vector_type(8)));

// Packed lower-block-triangular storage: tile(i,j), 0<=j<=i<=32, stored
// column-major by block-column. 561 tiles * 64KB = 36.8 MB.
__device__ __forceinline__ size_t tile_off(int i, int j) {
  return ((size_t)(j * NBLK - (j * (j - 1)) / 2 + (i - j))) * TILE_ELEMS;
}

// fp32 -> bf16 (round-to-nearest-even), raw bits; values are finite here.
__device__ __forceinline__ unsigned short f2bf(float f) {
  union { float f; unsigned int u; } v; v.f = f;
  unsigned int r = v.u + 0x7fffu + ((v.u >> 16) & 1u);
  return (unsigned short)(r >> 16);
}
__device__ __forceinline__ float bf2f(unsigned short b) {
  union { unsigned int u; float f; } v; v.u = ((unsigned int)b) << 16;
  return v.f;
}

// ---------------------------------------------------------------------------
// prep: fill stored tiles from the virtual bordered matrix.
// ---------------------------------------------------------------------------
__global__ __launch_bounds__(256) void prep(const float* __restrict__ Y,
                                            const float* __restrict__ mu,
                                            const float* __restrict__ Kp,
                                            const float* __restrict__ Sg,
                                            float* __restrict__ W) {
  int bid = blockIdx.x;
  int j = 0;
  while (j + 1 < NBLK) {
    int nxt = (j + 1) * NBLK - ((j + 1) * j) / 2;
    if (bid < nxt) break;
    ++j;
  }
  int start = j * NBLK - (j * (j - 1)) / 2;
  int i = j + (bid - start);
  float* T = W + tile_off(i, j);
  int tid = threadIdx.x;
  for (int idx = tid; idx < TILE_ELEMS; idx += 256) {
    int li = idx >> 7, lj = idx & 127;
    int gr = i * NB + li, gc = j * NB + lj;
    float v = 0.0f;
    if (gr < Nn) {
      v = Kp[(size_t)gr * Nn + gc];
      if (gr == gc) v += Sg[(size_t)gr * Nn + gr];
    } else {
      int b = gr - Nn;
      if (b < BSc && gc < Nn) v = mu[gc] - Y[(size_t)b * Nn + gc];
    }
    T[idx] = v;
  }
}

// ---------------------------------------------------------------------------
// potf2: factor tile(k,k) with recursive 32-blocking (unchanged, verified).
// ---------------------------------------------------------------------------
__global__ __launch_bounds__(256) void potf2(float* __restrict__ W, int k) {
  __shared__ float T[NB][NB + 1];
  __shared__ float dinv_sh[NBB];
  float* G = W + tile_off(k, k);
  int tid = threadIdx.x;
  for (int idx = tid; idx < TILE_ELEMS / 4; idx += 256) {
    float4 v = ((const float4*)G)[idx];
    int r = idx >> 5, c = (idx & 31) * 4;
    T[r][c] = v.x; T[r][c + 1] = v.y; T[r][c + 2] = v.z; T[r][c + 3] = v.w;
  }
  __syncthreads();
  int lane = tid & 63, wid = tid >> 6;
  for (int kb = 0; kb < 4; ++kb) {
    int o = kb * NBB;
    if (wid == 0) {
      int i = lane & 31;
      float cc[NBB];
#pragma unroll
      for (int p = 0; p < NBB; ++p) cc[p] = T[o + i][o + p];
#pragma unroll
      for (int j = 0; j < NBB; ++j) {
        float s = cc[j];
#pragma unroll
        for (int p = 0; p < NBB; ++p) {
          if (p < j) s -= cc[p] * __shfl(cc[p], j, 64);
        }
        float sj = __shfl(s, j, 64);
        float d = sqrtf(sj);
        if (i == j) cc[j] = d;
        else if (i > j) cc[j] = s / d;
      }
      if (lane < 32) {
#pragma unroll
        for (int p = 0; p < NBB; ++p) {
          if (p <= i) T[o + i][o + p] = cc[p];
        }
      }
    }
    __syncthreads();
    if (tid < NBB) dinv_sh[tid] = 1.0f / T[o + tid][o + tid];
    __syncthreads();
    int R = NB - o - NBB;
    if (R > 0) {
      if (tid < R) {
        int r = o + NBB + tid;
        float x[NBB];
#pragma unroll
        for (int p = 0; p < NBB; ++p) x[p] = T[r][o + p];
#pragma unroll
        for (int j = 0; j < NBB; ++j) {
          float s = x[j];
#pragma unroll
          for (int p = 0; p < NBB; ++p) {
            if (p < j) s -= x[p] * T[o + j][o + p];
          }
          x[j] = s * dinv_sh[j];
        }
#pragma unroll
        for (int p = 0; p < NBB; ++p) T[r][o + p] = x[p];
      }
      __syncthreads();
      int TL = R >> 2;
      int ntile = TL * (TL + 1) / 2;
      for (int t = tid; t < ntile; t += 256) {
        int ti = (int)((sqrtf(8.0f * t + 1.0f) - 1.0f) * 0.5f);
        while ((ti + 1) * (ti + 2) / 2 <= t) ++ti;
        while (ti * (ti + 1) / 2 > t) --ti;
        int tj = t - ti * (ti + 1) / 2;
        int tr = o + NBB + ti * 4, tc = o + NBB + tj * 4;
        float acc[4][4];
#pragma unroll
        for (int m = 0; m < 4; ++m)
#pragma unroll
          for (int n = 0; n < 4; ++n) acc[m][n] = 0.0f;
        for (int p = 0; p < NBB; ++p) {
          float a0 = T[tr][o + p], a1 = T[tr + 1][o + p],
                a2 = T[tr + 2][o + p], a3 = T[tr + 3][o + p];
          float b0 = T[tc][o + p], b1 = T[tc + 1][o + p],
                b2 = T[tc + 2][o + p], b3 = T[tc + 3][o + p];
          acc[0][0] += a0 * b0; acc[0][1] += a0 * b1; acc[0][2] += a0 * b2; acc[0][3] += a0 * b3;
          acc[1][0] += a1 * b0; acc[1][1] += a1 * b1; acc[1][2] += a1 * b2; acc[1][3] += a1 * b3;
          acc[2][0] += a2 * b0; acc[2][1] += a2 * b1; acc[2][2] += a2 * b2; acc[2][3] += a2 * b3;
          acc[3][0] += a3 * b0; acc[3][1] += a3 * b1; acc[3][2] += a3 * b2; acc[3][3] += a3 * b3;
        }
#pragma unroll
        for (int m = 0; m < 4; ++m)
#pragma unroll
          for (int n = 0; n < 4; ++n) T[tr + m][tc + n] -= acc[m][n];
      }
    }
    __syncthreads();
  }
  for (int idx = tid; idx < TILE_ELEMS; idx += 256) {
    int r = idx >> 7, c = idx & 127;
    if (c <= r) G[idx] = T[r][c];
  }
}

// ---------------------------------------------------------------------------
// trsm: tile(i,k) <- tile(i,k) * L_kk^{-T} (blocked, as before), then epilogue
// converts the solved panel to split-bf16 (hi/lo) global panels for syrk.
// fp32 panel writeback dropped (nothing reads it afterwards).
// ---------------------------------------------------------------------------
__global__ __launch_bounds__(256) void trsm(float* __restrict__ W,
                                            unsigned short* __restrict__ PH,
                                            unsigned short* __restrict__ PL,
                                            int k) {
  __shared__ float Td[NB][NB + 1];
  __shared__ float X[NB][NB + 1];
  __shared__ float dinv_sh[NB];
  int tid = threadIdx.x;
  int i = k + 1 + blockIdx.x;
  int rows = (i == NBLK - 1) ? BSc : NB;
  const float* Gd = W + tile_off(k, k);
  const float* Gx = W + tile_off(i, k);
  for (int idx = tid; idx < TILE_ELEMS / 4; idx += 256) {
    float4 v = ((const float4*)Gd)[idx];
    float4 u = ((const float4*)Gx)[idx];
    int r = idx >> 5, c = (idx & 31) * 4;
    Td[r][c] = v.x; Td[r][c + 1] = v.y; Td[r][c + 2] = v.z; Td[r][c + 3] = v.w;
    if (r < rows) { X[r][c] = u.x; X[r][c + 1] = u.y; X[r][c + 2] = u.z; X[r][c + 3] = u.w; }
    else          { X[r][c] = 0.0f; X[r][c + 1] = 0.0f; X[r][c + 2] = 0.0f; X[r][c + 3] = 0.0f; }
  }
  __syncthreads();
  if (tid < NB) dinv_sh[tid] = 1.0f / Td[tid][tid];
  __syncthreads();
  int rtile = (tid >> 3) * 4;
  int ctile = (tid & 7) * 4;
  for (int jb = 0; jb < 4; ++jb) {
    int o = jb * NBB;
    if (jb > 0) {
      float acc[4][4];
#pragma unroll
      for (int m = 0; m < 4; ++m)
#pragma unroll
        for (int n = 0; n < 4; ++n) acc[m][n] = 0.0f;
      for (int p = 0; p < o; ++p) {
        float a0 = X[rtile][p], a1 = X[rtile + 1][p],
              a2 = X[rtile + 2][p], a3 = X[rtile + 3][p];
        float b0 = Td[o + ctile][p], b1 = Td[o + ctile + 1][p],
              b2 = Td[o + ctile + 2][p], b3 = Td[o + ctile + 3][p];
        acc[0][0] += a0 * b0; acc[0][1] += a0 * b1; acc[0][2] += a0 * b2; acc[0][3] += a0 * b3;
        acc[1][0] += a1 * b0; acc[1][1] += a1 * b1; acc[1][2] += a1 * b2; acc[1][3] += a1 * b3;
        acc[2][0] += a2 * b0; acc[2][1] += a2 * b1; acc[2][2] += a2 * b2; acc[2][3] += a2 * b3;
        acc[3][0] += a3 * b0; acc[3][1] += a3 * b1; acc[3][2] += a3 * b2; acc[3][3] += a3 * b3;
      }
#pragma unroll
      for (int m = 0; m < 4; ++m)
#pragma unroll
        for (int n = 0; n < 4; ++n) X[rtile + m][o + ctile + n] -= acc[m][n];
      __syncthreads();
    }
    if (tid < NB) {
      int r = tid;
      float x[NBB];
#pragma unroll
      for (int p = 0; p < NBB; ++p) x[p] = X[r][o + p];
#pragma unroll
      for (int j = 0; j < NBB; ++j) {
        float s = x[j];
#pragma unroll
        for (int p = 0; p < NBB; ++p) {
          if (p < j) s -= x[p] * Td[o + j][o + p];
        }
        x[j] = s * dinv_sh[o + j];
      }
#pragma unroll
      for (int p = 0; p < NBB; ++p) X[r][o + p] = x[p];
    }
    __syncthreads();
  }
  // Epilogue: split-bf16 panel store (all 128 rows; dead border rows are 0).
  int r = tid >> 1, hf = tid & 1;
  unsigned short* ph = PH + (size_t)i * TILE_ELEMS + (size_t)r * NB + hf * 64;
  unsigned short* pl = PL + (size_t)i * TILE_ELEMS + (size_t)r * NB + hf * 64;
#pragma unroll
  for (int ch = 0; ch < 8; ++ch) {
    unsigned short hb[8], lb[8];
#pragma unroll
    for (int e = 0; e < 8; ++e) {
      float v = X[r][hf * 64 + ch * 8 + e];
      unsigned short h = f2bf(v);
      hb[e] = h;
      lb[e] = f2bf(v - bf2f(h));
    }
    *reinterpret_cast<uint4*>(&ph[ch * 8]) = *reinterpret_cast<const uint4*>(hb);
    *reinterpret_cast<uint4*>(&pl[ch * 8]) = *reinterpret_cast<const uint4*>(lb);
  }
}

// ---------------------------------------------------------------------------
// syrk: tile(i,j) -= P_i * P_j^T via split-bf16 MFMA (hi*hi + lo*hi + hi*lo),
// fp32 accumulate. 128x128 tile, 4 waves (2x2), 4x4 16x16 fragments per wave,
// K = 128 in 4 steps of 32. Panels pre-converted & zero-padded -> guard-free.
// ---------------------------------------------------------------------------
__global__ __launch_bounds__(256) void syrk(const unsigned short* __restrict__ PH,
                                            const unsigned short* __restrict__ PL,
                                            float* __restrict__ W, int k) {
  int i = k + 1 + blockIdx.x, j = k + 1 + blockIdx.y;
  if (i < j) return;
  const unsigned short* Ahg = PH + (size_t)i * TILE_ELEMS;
  const unsigned short* Alg = PL + (size_t)i * TILE_ELEMS;
  const unsigned short* Bhg = PH + (size_t)j * TILE_ELEMS;
  const unsigned short* Blg = PL + (size_t)j * TILE_ELEMS;
  float* C = W + tile_off(i, j);
  __shared__ unsigned short Ah[NB][40], Al[NB][40], Bh[NB][40], Bl[NB][40];
  int tid = threadIdx.x, lane = tid & 63, wid = tid >> 6;
  int wr = wid >> 1, wc = wid & 1, lm = lane & 15, lk = lane >> 4;
  f32x4 acc[4][4];
#pragma unroll
  for (int m = 0; m < 4; ++m)
#pragma unroll
    for (int n = 0; n < 4; ++n) acc[m][n] = (f32x4)0.0f;
  int r = tid >> 1, hf = tid & 1;
  for (int kb = 0; kb < 4; ++kb) {
    int kbase = kb * 32;
    if (kb) __syncthreads();
#pragma unroll
    for (int c = 0; c < 2; ++c) {
      int lc = (hf * 2 + c) * 8;          // LDS k-offset (bf16 elems)
      int kc = kbase + lc;                // global k-offset
      *reinterpret_cast<uint4*>(&Ah[r][lc]) = *reinterpret_cast<const uint4*>(&Ahg[(size_t)r * NB + kc]);
      *reinterpret_cast<uint4*>(&Al[r][lc]) = *reinterpret_cast<const uint4*>(&Alg[(size_t)r * NB + kc]);
      *reinterpret_cast<uint4*>(&Bh[r][lc]) = *reinterpret_cast<const uint4*>(&Bhg[(size_t)r * NB + kc]);
      *reinterpret_cast<uint4*>(&Bl[r][lc]) = *reinterpret_cast<const uint4*>(&Blg[(size_t)r * NB + kc]);
    }
    __syncthreads();
    bf16x8 ah[4], al[4], bh[4], bl[4];
#pragma unroll
    for (int mt = 0; mt < 4; ++mt) {
      int row = wr * 64 + mt * 16 + lm;
      ah[mt] = *reinterpret_cast<const bf16x8*>(&Ah[row][lk * 8]);
      al[mt] = *reinterpret_cast<const bf16x8*>(&Al[row][lk * 8]);
    }
#pragma unroll
    for (int nt = 0; nt < 4; ++nt) {
      int col = wc * 64 + nt * 16 + lm;
      bh[nt] = *reinterpret_cast<const bf16x8*>(&Bh[col][lk * 8]);
      bl[nt] = *reinterpret_cast<const bf16x8*>(&Bl[col][lk * 8]);
    }
#pragma unroll
    for (int mt = 0; mt < 4; ++mt)
#pragma unroll
      for (int nt = 0; nt < 4; ++nt) {
        acc[mt][nt] = __builtin_amdgcn_mfma_f32_16x16x32_bf16(ah[mt], bh[nt], acc[mt][nt], 0, 0, 0);
        acc[mt][nt] = __builtin_amdgcn_mfma_f32_16x16x32_bf16(al[mt], bh[nt], acc[mt][nt], 0, 0, 0);
        acc[mt][nt] = __builtin_amdgcn_mfma_f32_16x16x32_bf16(ah[mt], bl[nt], acc[mt][nt], 0, 0, 0);
      }
  }
#pragma unroll
  for (int mt = 0; mt < 4; ++mt)
#pragma unroll
    for (int nt = 0; nt < 4; ++nt) {
#pragma unroll
      for (int q = 0; q < 4; ++q) {
        int rr = wr * 64 + mt * 16 + lk * 4 + q;
        int cc = wc * 64 + nt * 16 + lm;
        C[rr * NB + cc] -= acc[mt][nt][q];
      }
    }
}

// ---------------------------------------------------------------------------
// finalize: -lml from corner trace and diag of L.
// ---------------------------------------------------------------------------
__global__ __launch_bounds__(256) void finalize(const float* __restrict__ W,
                                                const int* __restrict__ bsp,
                                                const int* __restrict__ tmaxp,
                                                float* __restrict__ out) {
  __shared__ float rl[4], rq[4];
  int tid = threadIdx.x;
  float lsum = 0.0f;
  for (int d = tid; d < Nn; d += 256) {
    int db = d >> 7, dl = d & 127;
    lsum += logf(W[tile_off(db, db) + (size_t)dl * NB + dl]);
  }
  float qsum = 0.0f;
  if (tid < BSc) qsum = W[tile_off(NBLK - 1, NBLK - 1) + (size_t)tid * NB + tid];
  for (int o = 32; o > 0; o >>= 1) {
    lsum += __shfl_down(lsum, o, 64);
    qsum += __shfl_down(qsum, o, 64);
  }
  int lane = tid & 63, wid = tid >> 6;
  if (lane == 0) { rl[wid] = lsum; rq[wid] = qsum; }
  __syncthreads();
  if (tid == 0) {
    float Lt = rl[0] + rl[1] + rl[2] + rl[3];
    float Qt = rq[0] + rq[1] + rq[2] + rq[3];
    float bsf = (float)bsp[0];
    float tmaxf = (float)tmaxp[0];
    out[0] = -Qt / (2.0f * bsf) + Lt + 0.5f * tmaxf * logf(6.283185307179586f);
  }
}

extern "C" void kernel_launch(void* const* d_in, const int* in_sizes, int n_in,
                              void* d_out, int out_size, void* d_ws, size_t ws_size,
                              hipStream_t stream) {
  const float* Y   = (const float*)d_in[0];
  const float* mu  = (const float*)d_in[1];
  const float* Kp  = (const float*)d_in[2];
  const float* Sg  = (const float*)d_in[3];
  const int*   bsp = (const int*)d_in[4];
  const int*   tmp_= (const int*)d_in[5];
  float* W = (float*)d_ws;                       // 561 tiles fp32: 36.8 MB
  unsigned short* PH = (unsigned short*)(W + (size_t)NTILES * TILE_ELEMS);  // 33 tiles bf16 hi
  unsigned short* PL = PH + (size_t)NBLK * TILE_ELEMS;                      // 33 tiles bf16 lo
  float* out = (float*)d_out;

  prep<<<NTILES, 256, 0, stream>>>(Y, mu, Kp, Sg, W);

  for (int k = 0; k < NK; ++k) {
    potf2<<<1, 256, 0, stream>>>(W, k);
    int T = NBLK - (k + 1);
    trsm<<<T, 256, 0, stream>>>(W, PH, PL, k);
    dim3 g(T, T);
    syrk<<<g, 256, 0, stream>>>(PH, PL, W, k);
  }
  finalize<<<1, 256, 0, stream>>>(W, bsp, tmp_, out);
}